// Round 7
// baseline (988.346 us; speedup 1.0000x reference)
//
#include <hip/hip_runtime.h>
#include <stdint.h>

#define NPTS 16384
#define BATCH 16
#define FPS_N 512
#define NANCH 50
#define TOPK 4
#define NBH 128
#define BALLK 1000

#define FT 512
#define PAIRS 16      // float2 pairs per thread = 32 pts
#define NW 8          // waves per block

#define CTRL_XOR1 0xB1
#define CTRL_XOR2 0x4E
#define CTRL_ROR4 0x124
#define CTRL_ROR8 0x128

#define DPP_MAX64(v, CTRL) do {                                                   \
  unsigned int _lo = (unsigned int)(v);                                           \
  unsigned int _hi = (unsigned int)((v) >> 32);                                   \
  unsigned int _slo = (unsigned int)__builtin_amdgcn_update_dpp((int)_lo, (int)_lo, CTRL, 0xf, 0xf, false); \
  unsigned int _shi = (unsigned int)__builtin_amdgcn_update_dpp((int)_hi, (int)_hi, CTRL, 0xf, 0xf, false); \
  unsigned long long _o = (((unsigned long long)_shi) << 32) | _slo;              \
  if (_o > (v)) (v) = _o;                                                         \
} while (0)

#define DPP_MIN64(v, CTRL) do {                                                   \
  unsigned int _lo = (unsigned int)(v);                                           \
  unsigned int _hi = (unsigned int)((v) >> 32);                                   \
  unsigned int _slo = (unsigned int)__builtin_amdgcn_update_dpp((int)_lo, (int)_lo, CTRL, 0xf, 0xf, false); \
  unsigned int _shi = (unsigned int)__builtin_amdgcn_update_dpp((int)_hi, (int)_hi, CTRL, 0xf, 0xf, false); \
  unsigned long long _o = (((unsigned long long)_shi) << 32) | _slo;              \
  if (_o < (v)) (v) = _o;                                                         \
} while (0)

#define SWZ16_MIN64(v) do {                                                       \
  unsigned int _lo = (unsigned int)(v), _hi = (unsigned int)((v) >> 32);          \
  unsigned int _slo = (unsigned int)__builtin_amdgcn_ds_swizzle((int)_lo, 0x401f);\
  unsigned int _shi = (unsigned int)__builtin_amdgcn_ds_swizzle((int)_hi, 0x401f);\
  unsigned long long _o = (((unsigned long long)_shi) << 32) | _slo;              \
  if (_o < (v)) (v) = _o;                                                         \
} while (0)

#define SHF32_MIN64(v) do {                                                       \
  unsigned long long _o = __shfl_xor((v), 32, 64);                                \
  if (_o < (v)) (v) = _o;                                                         \
} while (0)

__device__ __forceinline__ uint32_t f2key(float f) {
  uint32_t u = __float_as_uint(f);
  return (u & 0x80000000u) ? ~u : (u | 0x80000000u);
}

// One fused kernel. Blocks 0..15: full 512-step FPS, output written per step.
// Blocks 16..79 (b,j): 50-step seed FPS (bit-identical code), counts, top4,
// anchor-j 128-NN, roi1+roi2 output. NO global/LDS coord arrays: all coords in
// registers; per-step centroid comes from the winner wave's registers via LDS.
__global__ __launch_bounds__(FT, 2) void mega_kernel(const float* __restrict__ pts,
                                                     float* __restrict__ out) {
  __shared__ unsigned long long s_key[2][NW];
  __shared__ float4 s_xyz[2][NW];
  __shared__ float4 s_anch[NANCH];
  __shared__ int s_cnt[NANCH];
  __shared__ int s_t4[TOPK];
  __shared__ int s_knn[NBH];

  const int bid = blockIdx.x;
  const bool isFps = bid < BATCH;
  const int b = isFps ? bid : ((bid - BATCH) >> 2);
  const int j = (bid - BATCH) & 3;
  const int nsteps = isFps ? FPS_N : NANCH;

  const int t = threadIdx.x;
  const int lane = t & 63;
  const int wS = t >> 6;
  const float* __restrict__ px = pts + (size_t)b * 3 * NPTS;
  const float* __restrict__ py = px + NPTS;
  const float* __restrict__ pz = py + NPTS;

  // ---- coords fully in registers (128 VGPRs of arrays; cap 256 at 2 w/EU) ----
  float2 x2[PAIRS], y2[PAIRS], z2[PAIRS], dist2[PAIRS];
#pragma unroll
  for (int k = 0; k < PAIRS; ++k) {
    const int i2 = (k << 10) + (t << 1);
    x2[k] = *(const float2*)&px[i2];
    y2[k] = *(const float2*)&py[i2];
    z2[k] = *(const float2*)&pz[i2];
    dist2[k] = make_float2(1e10f, 1e10f);
  }
#pragma unroll
  for (int k = 0; k < PAIRS; ++k) {
    asm volatile("" : "+v"(x2[k]), "+v"(y2[k]), "+v"(z2[k]));
  }

  float bx = px[0], by = py[0], bz = pz[0];
  if (t == 0) {
    if (isFps) {
      float* o = out + ((size_t)b * 1536 + 1024) * 3;
      o[0] = bx; o[1] = by; o[2] = bz;
    } else {
      s_anch[0] = make_float4(bx, by, bz, 0.f);
    }
  }

  // ---- FPS loop: zero global traffic per step ----
  for (int step = 1; step < nsteps; ++step) {
    const int par = step & 1;
    const float2 nbx2 = make_float2(-bx, -bx);
    const float2 nby2 = make_float2(-by, -by);
    const float2 nbz2 = make_float2(-bz, -bz);
    float run = -1.0f;
#pragma unroll
    for (int k = 0; k < PAIRS; ++k) {
      float2 t0, t1, t2;
      // exact: d = ((x-bx)^2 + (y-by)^2) + (z-bz)^2, rn  (x + (-bx) == x - bx)
      asm("v_pk_add_f32 %0, %3, %6\n\t"
          "v_pk_add_f32 %1, %4, %7\n\t"
          "v_pk_add_f32 %2, %5, %8\n\t"
          "v_pk_mul_f32 %0, %0, %0\n\t"
          "v_pk_mul_f32 %1, %1, %1\n\t"
          "v_pk_mul_f32 %2, %2, %2\n\t"
          "v_pk_add_f32 %0, %0, %1\n\t"
          "v_pk_add_f32 %0, %0, %2"
          : "=&v"(t0), "=&v"(t1), "=&v"(t2)
          : "v"(x2[k]), "v"(y2[k]), "v"(z2[k]), "v"(nbx2), "v"(nby2), "v"(nbz2));
      dist2[k].x = fminf(dist2[k].x, t0.x);
      dist2[k].y = fminf(dist2[k].y, t0.y);
      asm("v_max3_f32 %0, %0, %1, %2"
          : "+v"(run) : "v"(dist2[k].x), "v"(dist2[k].y));
    }
    // wave max of value (u32 bit-order ok: dist >= 0)
    uint32_t m = __float_as_uint(run);
    {
      uint32_t s;
      s = (uint32_t)__builtin_amdgcn_update_dpp((int)m, (int)m, CTRL_XOR1, 0xf, 0xf, false); m = m > s ? m : s;
      s = (uint32_t)__builtin_amdgcn_update_dpp((int)m, (int)m, CTRL_XOR2, 0xf, 0xf, false); m = m > s ? m : s;
      s = (uint32_t)__builtin_amdgcn_update_dpp((int)m, (int)m, CTRL_ROR4, 0xf, 0xf, false); m = m > s ? m : s;
      s = (uint32_t)__builtin_amdgcn_update_dpp((int)m, (int)m, CTRL_ROR8, 0xf, 0xf, false); m = m > s ? m : s;
      s = (uint32_t)__builtin_amdgcn_ds_swizzle((int)m, 0x401f);                              m = m > s ? m : s;
      s = (uint32_t)__shfl_xor((int)m, 32, 64);                                              m = m > s ? m : s;
    }
    const float gmaxf = __uint_as_float(m);
    // first matching k = lowest index (k is the high bits of the point index);
    // the winner lane writes its candidate xyz from REGISTERS (static k index)
    uint32_t widx_w = 0u;
    bool done = false;
#pragma unroll
    for (int k = 0; k < PAIRS; ++k) {
      const unsigned long long b0 = __ballot(dist2[k].x == gmaxf);
      const unsigned long long b1 = __ballot(dist2[k].y == gmaxf);
      const unsigned long long cb = b0 | b1;
      if (!done && cb) {
        const int l = (int)__builtin_ctzll(cb);
        const uint32_t p = ((b0 >> l) & 1ull) ? 0u : 1u;
        widx_w = ((uint32_t)k << 10) + ((uint32_t)((wS << 6) | l) << 1) + p;
        if (lane == l) {
          const float cx = p ? x2[k].y : x2[k].x;
          const float cy = p ? y2[k].y : y2[k].x;
          const float cz = p ? z2[k].y : z2[k].x;
          s_xyz[par][wS] = make_float4(cx, cy, cz, 0.f);
        }
        done = true;
      }
    }
    if (lane == 0)
      s_key[par][wS] = ((unsigned long long)m << 32) | (uint32_t)(~widx_w);
    __syncthreads();
    unsigned long long g = s_key[par][lane & 7];
    const float4 cand = s_xyz[par][lane & 7];
    DPP_MAX64(g, CTRL_XOR1);
    DPP_MAX64(g, CTRL_XOR2);
    DPP_MAX64(g, CTRL_ROR4);   // alternating 4-groups -> all lanes hold the max
    const uint32_t widx = ~(uint32_t)g;
    const int wstar = (int)((widx >> 7) & 7);   // owning wave of point widx
    bx = __shfl(cand.x, wstar, 64);
    by = __shfl(cand.y, wstar, 64);
    bz = __shfl(cand.z, wstar, 64);
    if (t == 0) {
      if (isFps) {
        float* o = out + ((size_t)b * 1536 + 1024 + step) * 3;
        o[0] = bx; o[1] = by; o[2] = bz;   // fire-and-forget output write
      } else {
        s_anch[step] = make_float4(bx, by, bz, 0.f);
      }
    }
  }
  if (isFps) return;

  // ================= worker path (b, j) =================
  // psum per point, reference order (x^2 + y^2) + z^2
  float2 ps2[PAIRS];
#pragma unroll
  for (int k = 0; k < PAIRS; ++k) {
    float2 s0, s1, s2;
    asm("v_pk_mul_f32 %0, %3, %3\n\t"
        "v_pk_mul_f32 %1, %4, %4\n\t"
        "v_pk_mul_f32 %2, %5, %5\n\t"
        "v_pk_add_f32 %0, %0, %1\n\t"
        "v_pk_add_f32 %0, %0, %2"
        : "=&v"(s0), "=&v"(s1), "=&v"(s2)
        : "v"(x2[k]), "v"(y2[k]), "v"(z2[k]));
    ps2[k] = s0;
  }
  if (t < NANCH) s_cnt[t] = 0;
  __syncthreads();

  const float R2 = (float)(0.4 * 0.4);
  const float2 mm2 = make_float2(-2.0f, -2.0f);
  for (int a = 0; a < NANCH; ++a) {
    const float4 A = s_anch[a];
    const float ax = A.x, ay = A.y, az = A.z;
    const float asum = __fadd_rn(__fadd_rn(__fmul_rn(ax, ax), __fmul_rn(ay, ay)),
                                 __fmul_rn(az, az));
    const float2 ax2 = make_float2(ax, ax);
    const float2 ay2 = make_float2(ay, ay);
    const float2 az2 = make_float2(az, az);
    const float2 as2 = make_float2(asum, asum);
    int cw = 0;
#pragma unroll
    for (int k = 0; k < PAIRS; ++k) {
      float2 d0, d1, d2v;
      // per element: d = (((-2*(((ax*X)+(ay*Y))+(az*Z))) + asum) + psum), rn each
      asm("v_pk_mul_f32 %0, %3, %6\n\t"
          "v_pk_mul_f32 %1, %4, %7\n\t"
          "v_pk_mul_f32 %2, %5, %8\n\t"
          "v_pk_add_f32 %0, %0, %1\n\t"
          "v_pk_add_f32 %0, %0, %2\n\t"
          "v_pk_mul_f32 %0, %0, %9\n\t"
          "v_pk_add_f32 %0, %0, %10\n\t"
          "v_pk_add_f32 %0, %0, %11"
          : "=&v"(d0), "=&v"(d1), "=&v"(d2v)
          : "v"(x2[k]), "v"(y2[k]), "v"(z2[k]), "v"(ax2), "v"(ay2), "v"(az2),
            "v"(mm2), "v"(as2), "v"(ps2[k]));
      cw += (int)__popcll(__ballot(d0.x < R2));
      cw += (int)__popcll(__ballot(d0.y < R2));
    }
    if (lane == 0) atomicAdd(&s_cnt[a], cw);
  }
  __syncthreads();

  if (t == 0) {
    unsigned long long used = 0ULL;
    for (int r = 0; r < TOPK; ++r) {
      int bestc = -1, besta = 0;
      for (int a = 0; a < NANCH; ++a) {
        if (used & (1ULL << a)) continue;
        int c = s_cnt[a];
        c = c < BALLK ? c : BALLK;
        if (c > bestc) { bestc = c; besta = a; }   // strict > : lowest slot on ties
      }
      used |= 1ULL << besta;
      s_t4[r] = besta;
    }
  }
  __syncthreads();

  // ---- 128-NN for anchor j ----
  const float4 A = s_anch[s_t4[j]];
  const float ax = A.x, ay = A.y, az = A.z;
  const float asum = __fadd_rn(__fadd_rn(__fmul_rn(ax, ax), __fmul_rn(ay, ay)),
                               __fmul_rn(az, az));
  const float2 ax2 = make_float2(ax, ax);
  const float2 ay2 = make_float2(ay, ay);
  const float2 az2 = make_float2(az, az);
  const float2 as2 = make_float2(asum, asum);
  unsigned long long kk[2 * PAIRS];
#pragma unroll
  for (int k = 0; k < PAIRS; ++k) {
    float2 d0, d1, d2v;
    asm("v_pk_mul_f32 %0, %3, %6\n\t"
        "v_pk_mul_f32 %1, %4, %7\n\t"
        "v_pk_mul_f32 %2, %5, %8\n\t"
        "v_pk_add_f32 %0, %0, %1\n\t"
        "v_pk_add_f32 %0, %0, %2\n\t"
        "v_pk_mul_f32 %0, %0, %9\n\t"
        "v_pk_add_f32 %0, %0, %10\n\t"
        "v_pk_add_f32 %0, %0, %11"
        : "=&v"(d0), "=&v"(d1), "=&v"(d2v)
        : "v"(x2[k]), "v"(y2[k]), "v"(z2[k]), "v"(ax2), "v"(ay2), "v"(az2),
          "v"(mm2), "v"(as2), "v"(ps2[k]));
    const int i2 = (k << 10) + (t << 1);
    kk[2 * k]     = ((unsigned long long)f2key(d0.x) << 32) | (uint32_t)i2;
    kk[2 * k + 1] = ((unsigned long long)f2key(d0.y) << 32) | (uint32_t)(i2 + 1);
  }
  for (int r = 0; r < NBH; ++r) {
    unsigned long long v16[16];
#pragma unroll
    for (int k = 0; k < 16; ++k)
      v16[k] = kk[2 * k] < kk[2 * k + 1] ? kk[2 * k] : kk[2 * k + 1];
#pragma unroll
    for (int k = 0; k < 8; ++k) v16[k] = v16[k] < v16[k + 8] ? v16[k] : v16[k + 8];
#pragma unroll
    for (int k = 0; k < 4; ++k) v16[k] = v16[k] < v16[k + 4] ? v16[k] : v16[k + 4];
    unsigned long long m0 = v16[0] < v16[2] ? v16[0] : v16[2];
    unsigned long long m1 = v16[1] < v16[3] ? v16[1] : v16[3];
    unsigned long long m = m0 < m1 ? m0 : m1;

    DPP_MIN64(m, CTRL_XOR1);
    DPP_MIN64(m, CTRL_XOR2);
    DPP_MIN64(m, CTRL_ROR4);
    DPP_MIN64(m, CTRL_ROR8);
    SWZ16_MIN64(m);
    SHF32_MIN64(m);

    const int par = r & 1;
    if (lane == 0) s_key[par][wS] = m;
    __syncthreads();
    unsigned long long g = s_key[par][lane & 7];
    DPP_MIN64(g, CTRL_XOR1);
    DPP_MIN64(g, CTRL_XOR2);
    DPP_MIN64(g, CTRL_ROR4);
    if (t == 0) s_knn[r] = (int)(uint32_t)g;
#pragma unroll
    for (int k = 0; k < 2 * PAIRS; ++k)
      if (kk[k] == g) kk[k] = ~0ULL;  // remove winner (unique low bits)
  }
  __syncthreads();

  // final gather from global (off critical path; one parallel round trip)
  if (t < NBH) {
    const int idx = s_knn[t];
    const float X = px[idx], Y = py[idx], Z = pz[idx];
    float* o1 = out + ((size_t)b * 1536 + (j << 7) + t) * 3;
    float* o2 = o1 + 512 * 3;
    o1[0] = X; o1[1] = Y; o1[2] = Z;
    o2[0] = X; o2[1] = Y; o2[2] = Z;
  }
}

extern "C" void kernel_launch(void* const* d_in, const int* in_sizes, int n_in,
                              void* d_out, int out_size, void* d_ws, size_t ws_size,
                              hipStream_t stream) {
  const float* pts = (const float*)d_in[0];   // [16, 3, 16384]
  float* out = (float*)d_out;                 // [16, 1536, 3]
  (void)d_ws; (void)ws_size;
  mega_kernel<<<dim3(BATCH + BATCH * TOPK), dim3(FT), 0, stream>>>(pts, out);
}

// Round 8
// 927.306 us; speedup vs baseline: 1.0658x; 1.0658x over previous
//
#include <hip/hip_runtime.h>
#include <stdint.h>

#define NPTS 16384
#define BATCH 16
#define FPS_N 512
#define NANCH 50
#define TOPK 4
#define NBH 128
#define BALLK 1000

#define FT 512
#define NW 8

#define CTRL_XOR1 0xB1
#define CTRL_XOR2 0x4E
#define CTRL_ROR4 0x124
#define CTRL_ROR8 0x128

#define DPP_MAX64(v, CTRL) do {                                                   \
  unsigned int _lo = (unsigned int)(v);                                           \
  unsigned int _hi = (unsigned int)((v) >> 32);                                   \
  unsigned int _slo = (unsigned int)__builtin_amdgcn_update_dpp((int)_lo, (int)_lo, CTRL, 0xf, 0xf, false); \
  unsigned int _shi = (unsigned int)__builtin_amdgcn_update_dpp((int)_hi, (int)_hi, CTRL, 0xf, 0xf, false); \
  unsigned long long _o = (((unsigned long long)_shi) << 32) | _slo;              \
  if (_o > (v)) (v) = _o;                                                         \
} while (0)

#define DPP_MIN64(v, CTRL) do {                                                   \
  unsigned int _lo = (unsigned int)(v);                                           \
  unsigned int _hi = (unsigned int)((v) >> 32);                                   \
  unsigned int _slo = (unsigned int)__builtin_amdgcn_update_dpp((int)_lo, (int)_lo, CTRL, 0xf, 0xf, false); \
  unsigned int _shi = (unsigned int)__builtin_amdgcn_update_dpp((int)_hi, (int)_hi, CTRL, 0xf, 0xf, false); \
  unsigned long long _o = (((unsigned long long)_shi) << 32) | _slo;              \
  if (_o < (v)) (v) = _o;                                                         \
} while (0)

#define SWZ16_MIN64(v) do {                                                       \
  unsigned int _lo = (unsigned int)(v), _hi = (unsigned int)((v) >> 32);          \
  unsigned int _slo = (unsigned int)__builtin_amdgcn_ds_swizzle((int)_lo, 0x401f);\
  unsigned int _shi = (unsigned int)__builtin_amdgcn_ds_swizzle((int)_hi, 0x401f);\
  unsigned long long _o = (((unsigned long long)_shi) << 32) | _slo;              \
  if (_o < (v)) (v) = _o;                                                         \
} while (0)

#define SHF32_MIN64(v) do {                                                       \
  unsigned long long _o = __shfl_xor((v), 32, 64);                                \
  if (_o < (v)) (v) = _o;                                                         \
} while (0)

__device__ __forceinline__ uint32_t f2key(float f) {
  uint32_t u = __float_as_uint(f);
  return (u & 0x80000000u) ? ~u : (u | 0x80000000u);
}

#define REP16(OP) OP(0) OP(1) OP(2) OP(3) OP(4) OP(5) OP(6) OP(7) \
                  OP(8) OP(9) OP(10) OP(11) OP(12) OP(13) OP(14) OP(15)

// All per-point state as NAMED variables (no arrays -> no alloca -> no scratch).
__global__ __launch_bounds__(FT, 2) void mega_kernel(const float* __restrict__ pts,
                                                     float* __restrict__ out) {
  __shared__ unsigned long long s_key[2][NW];
  __shared__ float4 s_xyz[2][NW];
  __shared__ float4 s_anch[NANCH];
  __shared__ int s_cnt[NANCH];
  __shared__ int s_t4[TOPK];
  __shared__ int s_knn[NBH];

  const int bid = blockIdx.x;
  const bool isFps = bid < BATCH;
  const int b = isFps ? bid : ((bid - BATCH) >> 2);
  const int j = (bid - BATCH) & 3;
  const int nsteps = isFps ? FPS_N : NANCH;

  const int t = threadIdx.x;
  const int lane = t & 63;
  const int wS = t >> 6;
  const float* __restrict__ px = pts + (size_t)b * 3 * NPTS;
  const float* __restrict__ py = px + NPTS;
  const float* __restrict__ pz = py + NPTS;

  // ---- named per-pair state: x_k,y_k,z_k (coords), d_k (running min dist) ----
#define DECLK(k) float2 x_##k, y_##k, z_##k, d_##k;
  REP16(DECLK)
#undef DECLK
#define LOADK(k) { const int i2 = ((k) << 10) + (t << 1);                  \
    x_##k = *(const float2*)&px[i2];                                       \
    y_##k = *(const float2*)&py[i2];                                       \
    z_##k = *(const float2*)&pz[i2];                                       \
    d_##k = make_float2(1e10f, 1e10f); }
  REP16(LOADK)
#undef LOADK

  float bx = px[0], by = py[0], bz = pz[0];
  if (t == 0) {
    if (isFps) {
      float* o = out + ((size_t)b * 1536 + 1024) * 3;
      o[0] = bx; o[1] = by; o[2] = bz;
    } else {
      s_anch[0] = make_float4(bx, by, bz, 0.f);
    }
  }

  // ---- FPS loop: zero global traffic per step ----
  for (int step = 1; step < nsteps; ++step) {
    const int par = step & 1;
    const float2 nbx2 = make_float2(-bx, -bx);
    const float2 nby2 = make_float2(-by, -by);
    const float2 nbz2 = make_float2(-bz, -bz);
    float run = -1.0f;
    // exact: d = ((x-bx)^2 + (y-by)^2) + (z-bz)^2, rn (x + (-bx) == x - bx)
#define FPSK(k) {                                                          \
    float2 t0, t1, t2;                                                     \
    asm("v_pk_add_f32 %0, %3, %6\n\t"                                      \
        "v_pk_add_f32 %1, %4, %7\n\t"                                      \
        "v_pk_add_f32 %2, %5, %8\n\t"                                      \
        "v_pk_mul_f32 %0, %0, %0\n\t"                                      \
        "v_pk_mul_f32 %1, %1, %1\n\t"                                      \
        "v_pk_mul_f32 %2, %2, %2\n\t"                                      \
        "v_pk_add_f32 %0, %0, %1\n\t"                                      \
        "v_pk_add_f32 %0, %0, %2"                                          \
        : "=&v"(t0), "=&v"(t1), "=&v"(t2)                                  \
        : "v"(x_##k), "v"(y_##k), "v"(z_##k), "v"(nbx2), "v"(nby2), "v"(nbz2)); \
    d_##k.x = fminf(d_##k.x, t0.x);                                        \
    d_##k.y = fminf(d_##k.y, t0.y);                                        \
    asm("v_max3_f32 %0, %0, %1, %2"                                        \
        : "+v"(run) : "v"(d_##k.x), "v"(d_##k.y)); }
    REP16(FPSK)
#undef FPSK
    // wave max of value (u32 bit-order ok: dist >= 0)
    uint32_t m = __float_as_uint(run);
    {
      uint32_t s;
      s = (uint32_t)__builtin_amdgcn_update_dpp((int)m, (int)m, CTRL_XOR1, 0xf, 0xf, false); m = m > s ? m : s;
      s = (uint32_t)__builtin_amdgcn_update_dpp((int)m, (int)m, CTRL_XOR2, 0xf, 0xf, false); m = m > s ? m : s;
      s = (uint32_t)__builtin_amdgcn_update_dpp((int)m, (int)m, CTRL_ROR4, 0xf, 0xf, false); m = m > s ? m : s;
      s = (uint32_t)__builtin_amdgcn_update_dpp((int)m, (int)m, CTRL_ROR8, 0xf, 0xf, false); m = m > s ? m : s;
      s = (uint32_t)__builtin_amdgcn_ds_swizzle((int)m, 0x401f);                              m = m > s ? m : s;
      s = (uint32_t)__shfl_xor((int)m, 32, 64);                                              m = m > s ? m : s;
    }
    const float gmaxf = __uint_as_float(m);
    // lowest index achieving the wave max; winner lane stages xyz from registers
    uint32_t widx_w = 0u;
    bool done = false;
#define BALK(k) {                                                          \
    const unsigned long long b0 = __ballot(d_##k.x == gmaxf);              \
    const unsigned long long b1 = __ballot(d_##k.y == gmaxf);              \
    const unsigned long long cb = b0 | b1;                                 \
    if (!done && cb) {                                                     \
      const int l = (int)__builtin_ctzll(cb);                              \
      const uint32_t p = ((b0 >> l) & 1ull) ? 0u : 1u;                     \
      widx_w = ((uint32_t)(k) << 10) + ((uint32_t)((wS << 6) | l) << 1) + p; \
      if (lane == l) {                                                     \
        const float cx = p ? x_##k.y : x_##k.x;                            \
        const float cy = p ? y_##k.y : y_##k.x;                            \
        const float cz = p ? z_##k.y : z_##k.x;                            \
        s_xyz[par][wS] = make_float4(cx, cy, cz, 0.f);                     \
      }                                                                    \
      done = true;                                                         \
    } }
    REP16(BALK)
#undef BALK
    if (lane == 0)
      s_key[par][wS] = ((unsigned long long)m << 32) | (uint32_t)(~widx_w);
    __syncthreads();
    unsigned long long g = s_key[par][lane & 7];
    const float4 cand = s_xyz[par][lane & 7];
    DPP_MAX64(g, CTRL_XOR1);
    DPP_MAX64(g, CTRL_XOR2);
    DPP_MAX64(g, CTRL_ROR4);
    const uint32_t widx = ~(uint32_t)g;
    const int wstar = (int)((widx >> 7) & 7);
    bx = __shfl(cand.x, wstar, 64);
    by = __shfl(cand.y, wstar, 64);
    bz = __shfl(cand.z, wstar, 64);
    if (t == 0) {
      if (isFps) {
        float* o = out + ((size_t)b * 1536 + 1024 + step) * 3;
        o[0] = bx; o[1] = by; o[2] = bz;
      } else {
        s_anch[step] = make_float4(bx, by, bz, 0.f);
      }
    }
  }
  if (isFps) return;

  // ================= worker path (b, j) =================
  // psum per point, reference order (x^2 + y^2) + z^2
#define DECLP(k) float2 p_##k;
  REP16(DECLP)
#undef DECLP
#define PSUMK(k) {                                                         \
    float2 s0, s1, s2;                                                     \
    asm("v_pk_mul_f32 %0, %3, %3\n\t"                                      \
        "v_pk_mul_f32 %1, %4, %4\n\t"                                      \
        "v_pk_mul_f32 %2, %5, %5\n\t"                                      \
        "v_pk_add_f32 %0, %0, %1\n\t"                                      \
        "v_pk_add_f32 %0, %0, %2"                                          \
        : "=&v"(s0), "=&v"(s1), "=&v"(s2)                                  \
        : "v"(x_##k), "v"(y_##k), "v"(z_##k));                             \
    p_##k = s0; }
  REP16(PSUMK)
#undef PSUMK
  if (t < NANCH) s_cnt[t] = 0;
  __syncthreads();

  const float R2 = (float)(0.4 * 0.4);
  const float2 mm2 = make_float2(-2.0f, -2.0f);
  for (int a = 0; a < NANCH; ++a) {
    const float4 A = s_anch[a];
    const float ax = A.x, ay = A.y, az = A.z;
    const float asum = __fadd_rn(__fadd_rn(__fmul_rn(ax, ax), __fmul_rn(ay, ay)),
                                 __fmul_rn(az, az));
    const float2 ax2 = make_float2(ax, ax);
    const float2 ay2 = make_float2(ay, ay);
    const float2 az2 = make_float2(az, az);
    const float2 as2 = make_float2(asum, asum);
    int cw = 0;
    // per elem: d = (((-2*(((ax*X)+(ay*Y))+(az*Z))) + asum) + psum), rn each
#define CNTK(k) {                                                          \
    float2 d0, d1, d2v;                                                    \
    asm("v_pk_mul_f32 %0, %3, %6\n\t"                                      \
        "v_pk_mul_f32 %1, %4, %7\n\t"                                      \
        "v_pk_mul_f32 %2, %5, %8\n\t"                                      \
        "v_pk_add_f32 %0, %0, %1\n\t"                                      \
        "v_pk_add_f32 %0, %0, %2\n\t"                                      \
        "v_pk_mul_f32 %0, %0, %9\n\t"                                      \
        "v_pk_add_f32 %0, %0, %10\n\t"                                     \
        "v_pk_add_f32 %0, %0, %11"                                         \
        : "=&v"(d0), "=&v"(d1), "=&v"(d2v)                                 \
        : "v"(x_##k), "v"(y_##k), "v"(z_##k), "v"(ax2), "v"(ay2), "v"(az2),\
          "v"(mm2), "v"(as2), "v"(p_##k));                                 \
    cw += (int)__popcll(__ballot(d0.x < R2));                              \
    cw += (int)__popcll(__ballot(d0.y < R2)); }
    REP16(CNTK)
#undef CNTK
    if (lane == 0) atomicAdd(&s_cnt[a], cw);
  }
  __syncthreads();

  if (t == 0) {
    unsigned long long used = 0ULL;
    for (int r = 0; r < TOPK; ++r) {
      int bestc = -1, besta = 0;
      for (int a = 0; a < NANCH; ++a) {
        if (used & (1ULL << a)) continue;
        int c = s_cnt[a];
        c = c < BALLK ? c : BALLK;
        if (c > bestc) { bestc = c; besta = a; }   // strict > : lowest slot on ties
      }
      used |= 1ULL << besta;
      s_t4[r] = besta;
    }
  }
  __syncthreads();

  // ---- 128-NN for anchor j: keys as named u64 vars ----
  {
    const float4 A = s_anch[s_t4[j]];
    const float ax = A.x, ay = A.y, az = A.z;
    const float asum = __fadd_rn(__fadd_rn(__fmul_rn(ax, ax), __fmul_rn(ay, ay)),
                                 __fmul_rn(az, az));
    const float2 ax2 = make_float2(ax, ax);
    const float2 ay2 = make_float2(ay, ay);
    const float2 az2 = make_float2(az, az);
    const float2 as2 = make_float2(asum, asum);
#define DECLKK(k) unsigned long long ka_##k, kb_##k;
    REP16(DECLKK)
#undef DECLKK
#define KEYK(k) {                                                          \
    float2 d0, d1, d2v;                                                    \
    asm("v_pk_mul_f32 %0, %3, %6\n\t"                                      \
        "v_pk_mul_f32 %1, %4, %7\n\t"                                      \
        "v_pk_mul_f32 %2, %5, %8\n\t"                                      \
        "v_pk_add_f32 %0, %0, %1\n\t"                                      \
        "v_pk_add_f32 %0, %0, %2\n\t"                                      \
        "v_pk_mul_f32 %0, %0, %9\n\t"                                      \
        "v_pk_add_f32 %0, %0, %10\n\t"                                     \
        "v_pk_add_f32 %0, %0, %11"                                         \
        : "=&v"(d0), "=&v"(d1), "=&v"(d2v)                                 \
        : "v"(x_##k), "v"(y_##k), "v"(z_##k), "v"(ax2), "v"(ay2), "v"(az2),\
          "v"(mm2), "v"(as2), "v"(p_##k));                                 \
    const int i2 = ((k) << 10) + (t << 1);                                 \
    ka_##k = ((unsigned long long)f2key(d0.x) << 32) | (uint32_t)i2;       \
    kb_##k = ((unsigned long long)f2key(d0.y) << 32) | (uint32_t)(i2 + 1); }
    REP16(KEYK)
#undef KEYK
    for (int r = 0; r < NBH; ++r) {
#define PMINK(k) const unsigned long long w_##k = ka_##k < kb_##k ? ka_##k : kb_##k;
      REP16(PMINK)
#undef PMINK
      const unsigned long long q0 = w_0 < w_8 ? w_0 : w_8;
      const unsigned long long q1 = w_1 < w_9 ? w_1 : w_9;
      const unsigned long long q2 = w_2 < w_10 ? w_2 : w_10;
      const unsigned long long q3 = w_3 < w_11 ? w_3 : w_11;
      const unsigned long long q4 = w_4 < w_12 ? w_4 : w_12;
      const unsigned long long q5 = w_5 < w_13 ? w_5 : w_13;
      const unsigned long long q6 = w_6 < w_14 ? w_6 : w_14;
      const unsigned long long q7 = w_7 < w_15 ? w_7 : w_15;
      const unsigned long long r0 = q0 < q4 ? q0 : q4;
      const unsigned long long r1 = q1 < q5 ? q1 : q5;
      const unsigned long long r2 = q2 < q6 ? q2 : q6;
      const unsigned long long r3 = q3 < q7 ? q3 : q7;
      const unsigned long long s0 = r0 < r2 ? r0 : r2;
      const unsigned long long s1 = r1 < r3 ? r1 : r3;
      unsigned long long m = s0 < s1 ? s0 : s1;

      DPP_MIN64(m, CTRL_XOR1);
      DPP_MIN64(m, CTRL_XOR2);
      DPP_MIN64(m, CTRL_ROR4);
      DPP_MIN64(m, CTRL_ROR8);
      SWZ16_MIN64(m);
      SHF32_MIN64(m);

      const int par = r & 1;
      if (lane == 0) s_key[par][wS] = m;
      __syncthreads();
      unsigned long long g = s_key[par][lane & 7];
      DPP_MIN64(g, CTRL_XOR1);
      DPP_MIN64(g, CTRL_XOR2);
      DPP_MIN64(g, CTRL_ROR4);
      if (t == 0) s_knn[r] = (int)(uint32_t)g;
#define KILLK(k) { if (ka_##k == g) ka_##k = ~0ULL; if (kb_##k == g) kb_##k = ~0ULL; }
      REP16(KILLK)
#undef KILLK
    }
  }
  __syncthreads();

  // final gather from global (off critical path)
  if (t < NBH) {
    const int idx = s_knn[t];
    const float X = px[idx], Y = py[idx], Z = pz[idx];
    float* o1 = out + ((size_t)b * 1536 + (j << 7) + t) * 3;
    float* o2 = o1 + 512 * 3;
    o1[0] = X; o1[1] = Y; o1[2] = Z;
    o2[0] = X; o2[1] = Y; o2[2] = Z;
  }
}

extern "C" void kernel_launch(void* const* d_in, const int* in_sizes, int n_in,
                              void* d_out, int out_size, void* d_ws, size_t ws_size,
                              hipStream_t stream) {
  const float* pts = (const float*)d_in[0];   // [16, 3, 16384]
  float* out = (float*)d_out;                 // [16, 1536, 3]
  (void)d_ws; (void)ws_size;
  mega_kernel<<<dim3(BATCH + BATCH * TOPK), dim3(FT), 0, stream>>>(pts, out);
}